// Round 8
// baseline (484.023 us; speedup 1.0000x reference)
//
#include <hip/hip_runtime.h>
#include <cmath>

#define B_SZ  1024
#define NORB  128
#define NUP   32
#define HID   4096
#define NCORR (NORB * NUP)   // 4096
#define K1    (4 * NORB)     // 512, one-hot GEMM K-dim

typedef short    bf16x8 __attribute__((ext_vector_type(8)));
typedef _Float16 f16x8  __attribute__((ext_vector_type(8)));
typedef float    f32x4  __attribute__((ext_vector_type(4)));

__device__ __forceinline__ unsigned short f2bf_rne(float f) {
    unsigned int u = __float_as_uint(f);
    u += 0x7FFFu + ((u >> 16) & 1u);
    return (unsigned short)(u >> 16);
}

// ---------------------------------------------------------------------------
// k_splitW: W [rows][4096] f32 -> hi/lo bf16 in MFMA B-FRAGMENT ORDER
// (used for W1, ktTot=16). flat = ((nt*ktTot+kt)*64 + lane)*8 + j.
// ---------------------------------------------------------------------------
__global__ __launch_bounds__(256) void k_splitW(const float* __restrict__ W,
                                                unsigned short* __restrict__ Bph,
                                                unsigned short* __restrict__ Bpl,
                                                int ktTot) {
    __shared__ float tile[64][33];
    int n0 = blockIdx.x * 32, k0 = blockIdx.y * 64;
    int t = threadIdx.x;

    int rl = t >> 3, c4 = (t & 7) * 4;
#pragma unroll
    for (int i = 0; i < 2; ++i) {
        int kl = rl + 32 * i;
        float4 v = *(const float4*)(W + (size_t)(k0 + kl) * 4096 + n0 + c4);
        tile[kl][c4 + 0] = v.x; tile[kl][c4 + 1] = v.y;
        tile[kl][c4 + 2] = v.z; tile[kl][c4 + 3] = v.w;
    }
    __syncthreads();

    int nl = t & 31, kg = t >> 5;
    int nt = (n0 + nl) >> 4;
    int kt = (k0 >> 5) + (kg >> 2);
    int lane_o = (kg & 3) * 16 + (nl & 15);
    size_t o = (((size_t)nt * ktTot + kt) * 64 + lane_o) * 8;

    unsigned short hi8[8], lo8[8];
#pragma unroll
    for (int j = 0; j < 8; ++j) {
        float v = tile[kg * 8 + j][nl];
        unsigned short hi = f2bf_rne(v);
        float fhi = __uint_as_float((unsigned int)hi << 16);
        hi8[j] = hi;
        lo8[j] = f2bf_rne(v - fhi);
    }
    *(bf16x8*)(Bph + o) = *(bf16x8*)hi8;
    *(bf16x8*)(Bpl + o) = *(bf16x8*)lo8;
}

// ---------------------------------------------------------------------------
// k_hidden3: h = relu(one_hot(x) @ (W1hi + W1lo) + b1), f32 acc via bf16 MFMA.
// sched_barrier(0) pins the r0-r7 prefetch above the MFMA phase.
// ---------------------------------------------------------------------------
__global__ __launch_bounds__(256, 2) void k_hidden3(const int* __restrict__ x,
                                                    const unsigned short* __restrict__ Bph,
                                                    const unsigned short* __restrict__ Bpl,
                                                    const float* __restrict__ b1,
                                                    _Float16* __restrict__ h16) {
    __shared__ unsigned int sxp[64][8];                 //  2 KB
    __shared__ unsigned short BF[2][4][4][512];         // 32 KB
    __shared__ float Ht[64][132];                       // 33.8 KB

    int n0 = blockIdx.x * 128;
    int m0 = blockIdx.y * 64;
    int t = threadIdx.x;
    int w = t >> 6, lane = t & 63;
    int lm = lane & 15, kq = lane >> 4;
    int wn = w * 32;

    // pack x for this m-tile: 64 rows x 8 dwords (2 bits/orbital)
#pragma unroll
    for (int i = 0; i < 2; ++i) {
        int id = t + 256 * i;
        int row = id >> 3, d = id & 7;
        const int* src = x + (size_t)(m0 + row) * NORB + d * 16;
        unsigned int dw = 0;
#pragma unroll
        for (int b = 0; b < 16; ++b) dw |= ((unsigned int)(src[b] & 3)) << (2 * b);
        sxp[row][d] = dw;
    }

    int nt0 = (n0 + wn) >> 4;
    const unsigned short* bh0 = Bph + (size_t)nt0 * (16 * 512) + (size_t)lane * 8;
    const unsigned short* bh1 = Bph + (size_t)(nt0 + 1) * (16 * 512) + (size_t)lane * 8;
    const unsigned short* bl0 = Bpl + (size_t)nt0 * (16 * 512) + (size_t)lane * 8;
    const unsigned short* bl1 = Bpl + (size_t)(nt0 + 1) * (16 * 512) + (size_t)lane * 8;

    f32x4 acc[4][2] = {};

    bf16x8 r0 = *(const bf16x8*)(bh0);
    bf16x8 r1 = *(const bf16x8*)(bh1);
    bf16x8 r2 = *(const bf16x8*)(bl0);
    bf16x8 r3 = *(const bf16x8*)(bl1);
    bf16x8 r4 = *(const bf16x8*)(bh0 + 512);
    bf16x8 r5 = *(const bf16x8*)(bh1 + 512);
    bf16x8 r6 = *(const bf16x8*)(bl0 + 512);
    bf16x8 r7 = *(const bf16x8*)(bl1 + 512);

    __syncthreads();   // sxp ready

    for (int p = 0; p < 8; ++p) {
        if (p) __syncthreads();

        *(bf16x8*)&BF[0][w][0][lane * 8] = r0;
        *(bf16x8*)&BF[0][w][1][lane * 8] = r1;
        *(bf16x8*)&BF[0][w][2][lane * 8] = r2;
        *(bf16x8*)&BF[0][w][3][lane * 8] = r3;
        *(bf16x8*)&BF[1][w][0][lane * 8] = r4;
        *(bf16x8*)&BF[1][w][1][lane * 8] = r5;
        *(bf16x8*)&BF[1][w][2][lane * 8] = r6;
        *(bf16x8*)&BF[1][w][3][lane * 8] = r7;
        __syncthreads();

        int kn = (p + 1 < 8) ? p + 1 : 7;
        r0 = *(const bf16x8*)(bh0 + (2 * kn) * 512);
        r1 = *(const bf16x8*)(bh1 + (2 * kn) * 512);
        r2 = *(const bf16x8*)(bl0 + (2 * kn) * 512);
        r3 = *(const bf16x8*)(bl1 + (2 * kn) * 512);
        r4 = *(const bf16x8*)(bh0 + (2 * kn + 1) * 512);
        r5 = *(const bf16x8*)(bh1 + (2 * kn + 1) * 512);
        r6 = *(const bf16x8*)(bl0 + (2 * kn + 1) * 512);
        r7 = *(const bf16x8*)(bl1 + (2 * kn + 1) * 512);
        // Pin the prefetch ABOVE the MFMA phase.
        __builtin_amdgcn_sched_barrier(0);

#pragma unroll
        for (int s = 0; s < 2; ++s) {
            int kt = 2 * p + s;
            int i0 = kt * 8 + kq * 2;
            int dwIdx = i0 >> 4;
            int sh = (i0 & 15) * 2;
            bf16x8 af[4];
#pragma unroll
            for (int fm = 0; fm < 4; ++fm) {
                unsigned int dw = sxp[fm * 16 + lm][dwIdx];
                unsigned int c01 = (dw >> sh) & 0xFu;
                union { bf16x8 v; unsigned long long u[2]; } a;
                a.u[0] = 0x3F80ULL << ((c01 & 3u) * 16);
                a.u[1] = 0x3F80ULL << ((c01 >> 2) * 16);
                af[fm] = a.v;
            }

            bf16x8 b0h = *(const bf16x8*)&BF[s][w][0][lane * 8];
            bf16x8 b1h = *(const bf16x8*)&BF[s][w][1][lane * 8];
            bf16x8 b0l = *(const bf16x8*)&BF[s][w][2][lane * 8];
            bf16x8 b1l = *(const bf16x8*)&BF[s][w][3][lane * 8];

#pragma unroll
            for (int fm = 0; fm < 4; ++fm) {
                acc[fm][0] = __builtin_amdgcn_mfma_f32_16x16x32_bf16(af[fm], b0h, acc[fm][0], 0, 0, 0);
                acc[fm][0] = __builtin_amdgcn_mfma_f32_16x16x32_bf16(af[fm], b0l, acc[fm][0], 0, 0, 0);
                acc[fm][1] = __builtin_amdgcn_mfma_f32_16x16x32_bf16(af[fm], b1h, acc[fm][1], 0, 0, 0);
                acc[fm][1] = __builtin_amdgcn_mfma_f32_16x16x32_bf16(af[fm], b1l, acc[fm][1], 0, 0, 0);
            }
        }
    }

    // epilogue: bias+relu into LDS (D-layout), read back in A-frag order, f16
    __syncthreads();
#pragma unroll
    for (int fm = 0; fm < 4; ++fm)
#pragma unroll
        for (int fn = 0; fn < 2; ++fn) {
            int n = wn + fn * 16 + lm;
            float bv = b1[n0 + n];
#pragma unroll
            for (int r = 0; r < 4; ++r)
                Ht[fm * 16 + kq * 4 + r][n] = fmaxf(acc[fm][fn][r] + bv, 0.f);
        }
    __syncthreads();

    size_t mt0 = (size_t)(m0 >> 4), kt0 = (size_t)(n0 >> 5);
#pragma unroll
    for (int fi = 0; fi < 4; ++fi) {
        int f = w * 4 + fi;
        int mt = f >> 2, ktn = f & 3;
        int m = mt * 16 + lm;
        int kn = ktn * 32 + kq * 8;
        float4 v0 = *(const float4*)&Ht[m][kn];
        float4 v1 = *(const float4*)&Ht[m][kn + 4];
        float vv[8] = {v0.x, v0.y, v0.z, v0.w, v1.x, v1.y, v1.z, v1.w};
        f16x8 o16;
#pragma unroll
        for (int j = 0; j < 8; ++j) o16[j] = (_Float16)vv[j];
        size_t o = (((mt0 + mt) * 128 + (kt0 + ktn)) * 64 + lane) * 8;
        *(f16x8*)(h16 + o) = o16;
    }
}

// ---------------------------------------------------------------------------
// f32 fallback hidden
// ---------------------------------------------------------------------------
__global__ __launch_bounds__(256) void k_hidden_f32(const int* __restrict__ x,
                                                    const float* __restrict__ W1,
                                                    const float* __restrict__ b1,
                                                    float* __restrict__ h) {
    int b = blockIdx.x, tid = threadIdx.x;
    __shared__ int sx[NORB];
    if (tid < NORB) sx[tid] = x[b * NORB + tid];
    __syncthreads();
    float acc[16];
#pragma unroll
    for (int u = 0; u < 16; ++u) acc[u] = b1[tid + 256 * u];
    for (int i = 0; i < NORB; ++i) {
        const float* row = W1 + (size_t)(4 * i + sx[i]) * HID;
#pragma unroll
        for (int u = 0; u < 16; ++u) acc[u] += row[tid + 256 * u];
    }
    float* hb = h + (size_t)b * HID;
#pragma unroll
    for (int u = 0; u < 16; ++u) hb[tid + 256 * u] = fmaxf(acc[u], 0.f);
}

// ---------------------------------------------------------------------------
// k_gemm12: corr = h16 @ W2 + b2 with FUSED in-register hi/lo f16 split,
// W2 staged f32 through LDS (ROUND-POLISH r7).
// r7 evidence: gemm10's failure was 32 scalar strided dword loads + addr VALU
// (VALUBusy 46, 108us), NOT the conversion concept (total only +4 despite
// gemm +40; splitW16 measured ~36us by subtraction). Fix the load pattern:
//  - W2 tile 64k x 128n f32 staged via coalesced dwordx4 (64B segments),
//    reg-carried one iter ahead (r3's pinned-prefetch mechanism), ds_write
//    at iter top. Wt double-buffered -> SINGLE barrier/iter kept.
//  - Granule-rotation layout: src granule g of row r stored at slot
//    (g + 4*kq(r)) & 31 (kq(r)=(r>>3)&3). Writes: b128 start banks
//    4*scg+16*((q+skq)&1) -> uniform; reads: bank = lm + 16*((cc+kq)&1)
//    -> 2-way (free, m136). Zero pad: Wt[2] 64KB + AF[2] 16KB = 80KB
//    = exactly 2 blocks/CU (same occupancy as gemm7).
//  - Conversion hi=(f16)v, lo=(f16)((v-hi)*2048) bitwise == splitW16 output.
// Per-iter global bytes unchanged vs gemm7 (32KB f32 W2 == 32KB dual-f16).
// ---------------------------------------------------------------------------
__global__ __launch_bounds__(256, 2) void k_gemm12(const _Float16* __restrict__ Ap,
                                                   const float* __restrict__ W2f,
                                                   const float* __restrict__ bias,
                                                   float* __restrict__ C) {
    __shared__ float    Wt[2][64][128];     // 64 KB, granule-rotated
    __shared__ _Float16 AF[2][2][4][512];   // 16 KB

    int n0 = blockIdx.x * 128;
    int m0 = blockIdx.y * 64;
    int t = threadIdx.x;
    int w = t >> 6, lane = t & 63;
    int lm = lane & 15, kq = lane >> 4;
    int wn = w * 32;

    int mt0 = m0 >> 4;

    const _Float16* ag = Ap + (size_t)(mt0 + w) * 65536 + (size_t)lane * 8;

    // staging role: thread covers row srow, granules scg, scg+4, ..., scg+28
    int srow = t >> 2;
    int scg  = t & 3;
    int skq  = (srow >> 3) & 3;
    const float* wg0 = W2f + (size_t)srow * 4096 + n0;

    // per-lane read column offsets in the rotated layout:
    // element (row=32s+8*kq+j, col=32w+16cc+lm) lives at
    //   row*128 + ((colGranule + 4*kq)&31)*4 + (lm&3)
    int g0  = 8 * w + (lm >> 2) + 4 * kq;
    int co0 = ((g0 & 31) << 2) | (lm & 3);          // cc = 0
    int co1 = (((g0 + 4) & 31) << 2) | (lm & 3);    // cc = 1

    f32x4 accH[4][2] = {}, accL[4][2] = {};

    // prologue: tile 0 into regs
    f16x8 r0 = *(const f16x8*)(ag);
    f16x8 r1 = *(const f16x8*)(ag + 512);
    float4 wr[8];
#pragma unroll
    for (int q = 0; q < 8; ++q)
        wr[q] = *(const float4*)(wg0 + ((scg + 4 * q) << 2));

    for (int ktp = 0; ktp < 64; ++ktp) {
        int buf = ktp & 1;
#pragma unroll
        for (int q = 0; q < 8; ++q)
            *(float4*)&Wt[buf][srow][((scg + 4 * q + 4 * skq) & 31) << 2] = wr[q];
        *(f16x8*)&AF[buf][0][w][lane * 8] = r0;
        *(f16x8*)&AF[buf][1][w][lane * 8] = r1;
        __syncthreads();

        // prefetch tile ktp+1 (A + W2 f32), pinned above the compute phase so
        // the loads stay a full iteration ahead (r3-verified mechanism).
        int kn = (ktp + 1 < 64) ? ktp + 1 : 63;
        f16x8 nr0 = *(const f16x8*)(ag + (size_t)(2 * kn) * 512);
        f16x8 nr1 = *(const f16x8*)(ag + (size_t)(2 * kn + 1) * 512);
        const float* wgn = wg0 + (size_t)kn * 262144;   // 64 rows * 4096
        float4 nw[8];
#pragma unroll
        for (int q = 0; q < 8; ++q)
            nw[q] = *(const float4*)(wgn + ((scg + 4 * q) << 2));
        __builtin_amdgcn_sched_barrier(0);

        f16x8 a0[4], a1[4];
#pragma unroll
        for (int fm = 0; fm < 4; ++fm) {
            a0[fm] = *(const f16x8*)&AF[buf][0][fm][lane * 8];
            a1[fm] = *(const f16x8*)&AF[buf][1][fm][lane * 8];
        }

#pragma unroll
        for (int s = 0; s < 2; ++s) {
            const float* wrow = &Wt[buf][s * 32 + kq * 8][0];
            f16x8 bh0, bl0, bh1, bl1;
#pragma unroll
            for (int j = 0; j < 8; ++j) {
                float v0 = wrow[j * 128 + co0];
                _Float16 h0 = (_Float16)v0;
                bh0[j] = h0;
                bl0[j] = (_Float16)((v0 - (float)h0) * 2048.0f);
                float v1 = wrow[j * 128 + co1];
                _Float16 h1 = (_Float16)v1;
                bh1[j] = h1;
                bl1[j] = (_Float16)((v1 - (float)h1) * 2048.0f);
            }
#pragma unroll
            for (int fm = 0; fm < 4; ++fm) {
                f16x8 a = s ? a1[fm] : a0[fm];
                accH[fm][0] = __builtin_amdgcn_mfma_f32_16x16x32_f16(a, bh0, accH[fm][0], 0, 0, 0);
                accL[fm][0] = __builtin_amdgcn_mfma_f32_16x16x32_f16(a, bl0, accL[fm][0], 0, 0, 0);
                accH[fm][1] = __builtin_amdgcn_mfma_f32_16x16x32_f16(a, bh1, accH[fm][1], 0, 0, 0);
                accL[fm][1] = __builtin_amdgcn_mfma_f32_16x16x32_f16(a, bl1, accL[fm][1], 0, 0, 0);
            }
        }

        r0 = nr0; r1 = nr1;
#pragma unroll
        for (int q = 0; q < 8; ++q) wr[q] = nw[q];
    }

    const float ls = 1.0f / 2048.0f;
#pragma unroll
    for (int fm = 0; fm < 4; ++fm)
#pragma unroll
        for (int fn = 0; fn < 2; ++fn) {
            int n = n0 + wn + fn * 16 + lm;
            float bv = bias[n];
#pragma unroll
            for (int r = 0; r < 4; ++r) {
                int m = m0 + fm * 16 + kq * 4 + r;
                C[(size_t)m * NCORR + n] = accH[fm][fn][r] + ls * accL[fm][fn][r] + bv;
            }
        }
}

// ---------------------------------------------------------------------------
// f32 fallback GEMM (round-2 kernel, unchanged)
// ---------------------------------------------------------------------------
#define BM 64
#define BN 64
#define BK 32
__global__ __launch_bounds__(256) void k_gemm(const float* __restrict__ A,
                                              const float* __restrict__ Bm,
                                              const float* __restrict__ bias,
                                              float* __restrict__ C) {
    __shared__ float As[BK][68];
    __shared__ float Bs[BK][BN];
    int n0 = blockIdx.x * BN, m0 = blockIdx.y * BM;
    int tid = threadIdx.x;
    int tm = tid >> 4, tn = tid & 15;
    int am = tid >> 3, ak = (tid & 7) * 4;
    int bk = tid >> 4, bn = (tid & 15) * 4;
    float acc[4][4] = {};
    for (int k0 = 0; k0 < HID; k0 += BK) {
#pragma unroll
        for (int s = 0; s < 2; ++s) {
            int m = am + 32 * s;
            float4 v = *(const float4*)(A + (size_t)(m0 + m) * HID + k0 + ak);
            As[ak + 0][m] = v.x; As[ak + 1][m] = v.y;
            As[ak + 2][m] = v.z; As[ak + 3][m] = v.w;
        }
#pragma unroll
        for (int s = 0; s < 2; ++s) {
            int k = bk + 16 * s;
            float4 v = *(const float4*)(Bm + (size_t)(k0 + k) * NCORR + n0 + bn);
            *(float4*)&Bs[k][bn] = v;
        }
        __syncthreads();
#pragma unroll
        for (int kk = 0; kk < BK; ++kk) {
            float4 a = *(const float4*)&As[kk][tm * 4];
            float4 bv = *(const float4*)&Bs[kk][tn * 4];
            float av[4] = {a.x, a.y, a.z, a.w};
            float bb[4] = {bv.x, bv.y, bv.z, bv.w};
#pragma unroll
            for (int i = 0; i < 4; ++i)
#pragma unroll
                for (int j = 0; j < 4; ++j) acc[i][j] += av[i] * bb[j];
        }
        __syncthreads();
    }
#pragma unroll
    for (int i = 0; i < 4; ++i) {
        int m = m0 + tm * 4 + i;
        float4 o;
        o.x = acc[i][0] + bias[n0 + tn * 4 + 0];
        o.y = acc[i][1] + bias[n0 + tn * 4 + 1];
        o.z = acc[i][2] + bias[n0 + tn * 4 + 2];
        o.w = acc[i][3] + bias[n0 + tn * 4 + 3];
        *(float4*)(C + (size_t)m * NCORR + n0 + tn * 4) = o;
    }
}

// ---------------------------------------------------------------------------
// Kernel C: gather + 32x32 LU (partial pivoting) per spin, planar complex out.
// ---------------------------------------------------------------------------
__global__ __launch_bounds__(128) void k_det(const int* __restrict__ x,
                                             const float* __restrict__ orbitals,
                                             const float* __restrict__ corr,
                                             float* __restrict__ out,
                                             int imag_off) {
    int b = blockIdx.x, tid = threadIdx.x;
    __shared__ int sx[NORB];
    __shared__ int yup[NUP], ydn[NUP];
    __shared__ float M[2][NUP][NUP + 1];
    __shared__ float rlog[2];
    __shared__ int rneg[2];

    sx[tid] = x[b * NORB + tid];
    __syncthreads();

    int occ = sx[tid];
    if (occ & 1) {
        int r = 0;
        for (int i = 0; i < tid; ++i) r += sx[i] & 1;
        yup[r] = tid;
    }
    if (occ & 2) {
        int r = 0;
        for (int i = 0; i < tid; ++i) r += (sx[i] >> 1) & 1;
        ydn[r] = tid;
    }
    __syncthreads();

    const float* cb = corr + (size_t)b * NCORR;
    for (int idx = tid; idx < 2 * NUP * NUP; idx += 128) {
        int s = idx >> 10;
        int i = (idx >> 5) & 31;
        int j = idx & 31;
        int r = s ? ydn[i] : yup[i];
        M[s][i][j] = orbitals[r * NUP + j] + cb[r * NUP + j];
    }
    __syncthreads();

    int wv = tid >> 6, lane = tid & 63;
    float (*Mm)[NUP + 1] = M[wv];
    float logdet = 0.f;
    int neg = 0;

    for (int k = 0; k < NUP; ++k) {
        float v = (lane >= k && lane < NUP) ? fabsf(Mm[lane][k]) : -1.f;
        int pi = lane;
#pragma unroll
        for (int off = 32; off > 0; off >>= 1) {
            float v2 = __shfl_down(v, off);
            int p2 = __shfl_down(pi, off);
            if (v2 > v) { v = v2; pi = p2; }
        }
        int p = __shfl(pi, 0);

        if (p != k) {
            if (lane < NUP) {
                float t1 = Mm[k][lane];
                Mm[k][lane] = Mm[p][lane];
                Mm[p][lane] = t1;
            }
            neg ^= 1;
        }
        __syncthreads();

        float pv = Mm[k][k];
        logdet += logf(fabsf(pv));
        if (pv < 0.f) neg ^= 1;

        int row = k + 1 + (lane & 31);
        int half = lane >> 5;
        if (row < NUP) {
            float f = Mm[row][k] / pv;
            for (int j = k + 1 + half; j < NUP; j += 2)
                Mm[row][j] -= f * Mm[k][j];
        }
        __syncthreads();
    }

    if (lane == 0) { rlog[wv] = logdet; rneg[wv] = neg; }
    __syncthreads();
    if (tid == 0) {
        out[b] = rlog[0] + rlog[1];
        if (imag_off > 0)
            out[imag_off + b] =
                (rneg[0] ^ rneg[1]) ? 3.14159265358979323846f : 0.f;
    }
}

// ---------------------------------------------------------------------------
extern "C" void kernel_launch(void* const* d_in, const int* in_sizes, int n_in,
                              void* d_out, int out_size, void* d_ws, size_t ws_size,
                              hipStream_t stream) {
    const int*   x        = (const int*)d_in[0];
    const float* orbitals = (const float*)d_in[1];
    const float* W1       = (const float*)d_in[2];
    const float* b1       = (const float*)d_in[3];
    const float* W2       = (const float*)d_in[4];
    const float* b2       = (const float*)d_in[5];
    float* out = (float*)d_out;
    int imag_off = (out_size == 2 * B_SZ) ? B_SZ : 0;

    const size_t need = (size_t)32 * 1024 * 1024;
    if (ws_size >= need) {
        _Float16* h16  = (_Float16*)d_ws;                                //  8 MB (A-frag packed f16)
        float*    corr = (float*)(h16 + (size_t)B_SZ * HID);             // 16 MB

        // W1-pack (bf16) lives INSIDE corr — written by k_splitW, read by
        // k_hidden3, overwritten later by k_gemm12's corr output.
        unsigned short* W1ph = (unsigned short*)corr;                    // 4 MB
        unsigned short* W1pl = W1ph + (size_t)K1 * HID;                  // 4 MB

        // 1) W1 pack
        k_splitW<<<dim3(HID / 32, K1 / 64), 256, 0, stream>>>(W1, W1ph, W1pl, 16);

        // 2) hidden layer
        k_hidden3<<<dim3(HID / 128, B_SZ / 64), 256, 0, stream>>>(x, W1ph, W1pl, b1, h16);

        // 3) main GEMM, fused W2 split via LDS-transposed f32 staging
        dim3 g2(NCORR / 128, B_SZ / 64);    // 32 x 16 = 512 blocks
        k_gemm12<<<g2, 256, 0, stream>>>(h16, W2, b2, corr);

        // 4) determinants
        k_det<<<B_SZ, 128, 0, stream>>>(x, orbitals, corr, out, imag_off);
    } else {
        float* h    = (float*)d_ws;
        float* corr = h + (size_t)B_SZ * HID;
        k_hidden_f32<<<B_SZ, 256, 0, stream>>>(x, W1, b1, h);
        dim3 g2(NCORR / BN, B_SZ / BM);
        k_gemm<<<g2, 256, 0, stream>>>(h, W2, b2, corr);
        k_det<<<B_SZ, 128, 0, stream>>>(x, orbitals, corr, out, imag_off);
    }
}

// Round 9
// 239.370 us; speedup vs baseline: 2.0221x; 2.0221x over previous
//
#include <hip/hip_runtime.h>
#include <cmath>

#define B_SZ  1024
#define NORB  128
#define NUP   32
#define HID   4096
#define NCORR (NORB * NUP)   // 4096
#define K1    (4 * NORB)     // 512, one-hot GEMM K-dim

typedef short    bf16x8 __attribute__((ext_vector_type(8)));
typedef _Float16 f16x8  __attribute__((ext_vector_type(8)));
typedef float    f32x4  __attribute__((ext_vector_type(4)));

__device__ __forceinline__ unsigned short f2bf_rne(float f) {
    unsigned int u = __float_as_uint(f);
    u += 0x7FFFu + ((u >> 16) & 1u);
    return (unsigned short)(u >> 16);
}

// ---------------------------------------------------------------------------
// k_pack: MERGED W1-pack + W2-pack (ROUND-POLISH r8).
// r8 evidence: fused-into-GEMM W2 split failed twice (r7: scalar strided
// loads, 108us; r8: register blowout -> 500MB scratch spill + LDS conflicts,
// 350us). Fusion branch closed; packs stay separate kernels. But the TWO pack
// kernels are independent and shape-identical (256 thr, 8.4KB LDS tile, same
// load/transpose) -> one dispatch, block-role split. Unlike the r5 mistake
// (union with hidden3's 68KB LDS: occupancy collapse, +11us), this merge is
// occupancy-neutral. Saves one launch gap; W1 pack overlaps W2 pack.
//   blocks [0,1024):    W1 [512][4096] -> bf16 hi/lo, B-frag order, ktTot=16
//   blocks [1024,9216): W2 [4096][4096] -> f16 hi + f16 lo*2048, ktTot=128
// lo*2048 keeps W2_lo in f16 normal range; gemm7 epilogue applies 1/2048.
// ---------------------------------------------------------------------------
__global__ __launch_bounds__(256) void k_pack(const float* __restrict__ W1,
                                              unsigned short* __restrict__ W1ph,
                                              unsigned short* __restrict__ W1pl,
                                              const float* __restrict__ W2,
                                              _Float16* __restrict__ Bh16,
                                              _Float16* __restrict__ Bl16) {
    __shared__ float tile[64][33];
    int bid = blockIdx.x;
    int t = threadIdx.x;

    int isW2 = (bid >= 1024);
    int i = isW2 ? bid - 1024 : bid;
    int n0 = (i & 127) * 32;
    int k0 = (i >> 7) * 64;
    const float* W = isW2 ? W2 : W1;

    int rl = t >> 3, c4 = (t & 7) * 4;
#pragma unroll
    for (int q = 0; q < 2; ++q) {
        int kl = rl + 32 * q;
        float4 v = *(const float4*)(W + (size_t)(k0 + kl) * 4096 + n0 + c4);
        tile[kl][c4 + 0] = v.x; tile[kl][c4 + 1] = v.y;
        tile[kl][c4 + 2] = v.z; tile[kl][c4 + 3] = v.w;
    }
    __syncthreads();

    int nl = t & 31, kg = t >> 5;
    int nt = (n0 + nl) >> 4;
    int kt = (k0 >> 5) + (kg >> 2);
    int lane_o = (kg & 3) * 16 + (nl & 15);

    if (isW2) {
        size_t o = (((size_t)nt * 128 + kt) * 64 + lane_o) * 8;
        f16x8 hi8, lo8;
#pragma unroll
        for (int j = 0; j < 8; ++j) {
            float v = tile[kg * 8 + j][nl];
            _Float16 hi = (_Float16)v;
            hi8[j] = hi;
            lo8[j] = (_Float16)((v - (float)hi) * 2048.0f);
        }
        *(f16x8*)(Bh16 + o) = hi8;
        *(f16x8*)(Bl16 + o) = lo8;
    } else {
        size_t o = (((size_t)nt * 16 + kt) * 64 + lane_o) * 8;
        unsigned short hi8[8], lo8[8];
#pragma unroll
        for (int j = 0; j < 8; ++j) {
            float v = tile[kg * 8 + j][nl];
            unsigned short hi = f2bf_rne(v);
            float fhi = __uint_as_float((unsigned int)hi << 16);
            hi8[j] = hi;
            lo8[j] = f2bf_rne(v - fhi);
        }
        *(bf16x8*)(W1ph + o) = *(bf16x8*)hi8;
        *(bf16x8*)(W1pl + o) = *(bf16x8*)lo8;
    }
}

// ---------------------------------------------------------------------------
// k_hidden3: h = relu(one_hot(x) @ (W1hi + W1lo) + b1), f32 acc via bf16 MFMA.
// sched_barrier(0) pins the r0-r7 prefetch above the MFMA phase.
// (r3-verified version, unchanged.)
// ---------------------------------------------------------------------------
__global__ __launch_bounds__(256, 2) void k_hidden3(const int* __restrict__ x,
                                                    const unsigned short* __restrict__ Bph,
                                                    const unsigned short* __restrict__ Bpl,
                                                    const float* __restrict__ b1,
                                                    _Float16* __restrict__ h16) {
    __shared__ unsigned int sxp[64][8];                 //  2 KB
    __shared__ unsigned short BF[2][4][4][512];         // 32 KB
    __shared__ float Ht[64][132];                       // 33.8 KB

    int n0 = blockIdx.x * 128;
    int m0 = blockIdx.y * 64;
    int t = threadIdx.x;
    int w = t >> 6, lane = t & 63;
    int lm = lane & 15, kq = lane >> 4;
    int wn = w * 32;

    // pack x for this m-tile: 64 rows x 8 dwords (2 bits/orbital)
#pragma unroll
    for (int i = 0; i < 2; ++i) {
        int id = t + 256 * i;
        int row = id >> 3, d = id & 7;
        const int* src = x + (size_t)(m0 + row) * NORB + d * 16;
        unsigned int dw = 0;
#pragma unroll
        for (int b = 0; b < 16; ++b) dw |= ((unsigned int)(src[b] & 3)) << (2 * b);
        sxp[row][d] = dw;
    }

    int nt0 = (n0 + wn) >> 4;
    const unsigned short* bh0 = Bph + (size_t)nt0 * (16 * 512) + (size_t)lane * 8;
    const unsigned short* bh1 = Bph + (size_t)(nt0 + 1) * (16 * 512) + (size_t)lane * 8;
    const unsigned short* bl0 = Bpl + (size_t)nt0 * (16 * 512) + (size_t)lane * 8;
    const unsigned short* bl1 = Bpl + (size_t)(nt0 + 1) * (16 * 512) + (size_t)lane * 8;

    f32x4 acc[4][2] = {};

    bf16x8 r0 = *(const bf16x8*)(bh0);
    bf16x8 r1 = *(const bf16x8*)(bh1);
    bf16x8 r2 = *(const bf16x8*)(bl0);
    bf16x8 r3 = *(const bf16x8*)(bl1);
    bf16x8 r4 = *(const bf16x8*)(bh0 + 512);
    bf16x8 r5 = *(const bf16x8*)(bh1 + 512);
    bf16x8 r6 = *(const bf16x8*)(bl0 + 512);
    bf16x8 r7 = *(const bf16x8*)(bl1 + 512);

    __syncthreads();   // sxp ready

    for (int p = 0; p < 8; ++p) {
        if (p) __syncthreads();

        *(bf16x8*)&BF[0][w][0][lane * 8] = r0;
        *(bf16x8*)&BF[0][w][1][lane * 8] = r1;
        *(bf16x8*)&BF[0][w][2][lane * 8] = r2;
        *(bf16x8*)&BF[0][w][3][lane * 8] = r3;
        *(bf16x8*)&BF[1][w][0][lane * 8] = r4;
        *(bf16x8*)&BF[1][w][1][lane * 8] = r5;
        *(bf16x8*)&BF[1][w][2][lane * 8] = r6;
        *(bf16x8*)&BF[1][w][3][lane * 8] = r7;
        __syncthreads();

        int kn = (p + 1 < 8) ? p + 1 : 7;
        r0 = *(const bf16x8*)(bh0 + (2 * kn) * 512);
        r1 = *(const bf16x8*)(bh1 + (2 * kn) * 512);
        r2 = *(const bf16x8*)(bl0 + (2 * kn) * 512);
        r3 = *(const bf16x8*)(bl1 + (2 * kn) * 512);
        r4 = *(const bf16x8*)(bh0 + (2 * kn + 1) * 512);
        r5 = *(const bf16x8*)(bh1 + (2 * kn + 1) * 512);
        r6 = *(const bf16x8*)(bl0 + (2 * kn + 1) * 512);
        r7 = *(const bf16x8*)(bl1 + (2 * kn + 1) * 512);
        // Pin the prefetch ABOVE the MFMA phase.
        __builtin_amdgcn_sched_barrier(0);

#pragma unroll
        for (int s = 0; s < 2; ++s) {
            int kt = 2 * p + s;
            int i0 = kt * 8 + kq * 2;
            int dwIdx = i0 >> 4;
            int sh = (i0 & 15) * 2;
            bf16x8 af[4];
#pragma unroll
            for (int fm = 0; fm < 4; ++fm) {
                unsigned int dw = sxp[fm * 16 + lm][dwIdx];
                unsigned int c01 = (dw >> sh) & 0xFu;
                union { bf16x8 v; unsigned long long u[2]; } a;
                a.u[0] = 0x3F80ULL << ((c01 & 3u) * 16);
                a.u[1] = 0x3F80ULL << ((c01 >> 2) * 16);
                af[fm] = a.v;
            }

            bf16x8 b0h = *(const bf16x8*)&BF[s][w][0][lane * 8];
            bf16x8 b1h = *(const bf16x8*)&BF[s][w][1][lane * 8];
            bf16x8 b0l = *(const bf16x8*)&BF[s][w][2][lane * 8];
            bf16x8 b1l = *(const bf16x8*)&BF[s][w][3][lane * 8];

#pragma unroll
            for (int fm = 0; fm < 4; ++fm) {
                acc[fm][0] = __builtin_amdgcn_mfma_f32_16x16x32_bf16(af[fm], b0h, acc[fm][0], 0, 0, 0);
                acc[fm][0] = __builtin_amdgcn_mfma_f32_16x16x32_bf16(af[fm], b0l, acc[fm][0], 0, 0, 0);
                acc[fm][1] = __builtin_amdgcn_mfma_f32_16x16x32_bf16(af[fm], b1h, acc[fm][1], 0, 0, 0);
                acc[fm][1] = __builtin_amdgcn_mfma_f32_16x16x32_bf16(af[fm], b1l, acc[fm][1], 0, 0, 0);
            }
        }
    }

    // epilogue: bias+relu into LDS (D-layout), read back in A-frag order, f16
    __syncthreads();
#pragma unroll
    for (int fm = 0; fm < 4; ++fm)
#pragma unroll
        for (int fn = 0; fn < 2; ++fn) {
            int n = wn + fn * 16 + lm;
            float bv = b1[n0 + n];
#pragma unroll
            for (int r = 0; r < 4; ++r)
                Ht[fm * 16 + kq * 4 + r][n] = fmaxf(acc[fm][fn][r] + bv, 0.f);
        }
    __syncthreads();

    size_t mt0 = (size_t)(m0 >> 4), kt0 = (size_t)(n0 >> 5);
#pragma unroll
    for (int fi = 0; fi < 4; ++fi) {
        int f = w * 4 + fi;
        int mt = f >> 2, ktn = f & 3;
        int m = mt * 16 + lm;
        int kn = ktn * 32 + kq * 8;
        float4 v0 = *(const float4*)&Ht[m][kn];
        float4 v1 = *(const float4*)&Ht[m][kn + 4];
        float vv[8] = {v0.x, v0.y, v0.z, v0.w, v1.x, v1.y, v1.z, v1.w};
        f16x8 o16;
#pragma unroll
        for (int j = 0; j < 8; ++j) o16[j] = (_Float16)vv[j];
        size_t o = (((mt0 + mt) * 128 + (kt0 + ktn)) * 64 + lane) * 8;
        *(f16x8*)(h16 + o) = o16;
    }
}

// ---------------------------------------------------------------------------
// f32 fallback hidden
// ---------------------------------------------------------------------------
__global__ __launch_bounds__(256) void k_hidden_f32(const int* __restrict__ x,
                                                    const float* __restrict__ W1,
                                                    const float* __restrict__ b1,
                                                    float* __restrict__ h) {
    int b = blockIdx.x, tid = threadIdx.x;
    __shared__ int sx[NORB];
    if (tid < NORB) sx[tid] = x[b * NORB + tid];
    __syncthreads();
    float acc[16];
#pragma unroll
    for (int u = 0; u < 16; ++u) acc[u] = b1[tid + 256 * u];
    for (int i = 0; i < NORB; ++i) {
        const float* row = W1 + (size_t)(4 * i + sx[i]) * HID;
#pragma unroll
        for (int u = 0; u < 16; ++u) acc[u] += row[tid + 256 * u];
    }
    float* hb = h + (size_t)b * HID;
#pragma unroll
    for (int u = 0; u < 16; ++u) hb[tid + 256 * u] = fmaxf(acc[u], 0.f);
}

// ---------------------------------------------------------------------------
// k_gemm7: corr = h16 @ W2hi16 + (h16 @ W2lo16')/2048 + b2, f16 MFMA, f32 acc.
// r3-verified best (67.3/68.4us measured twice): one-iter software pipeline,
// AF double-buffered, single barrier/iter, sched_barrier(0) pinning the
// 10-load prefetch cluster. At the 2-barrier-structure ceiling (~1020 TF
// effective = 41% dense peak); r4 (occupancy 2x), r5 (128-row tile), r7/r8
// (fused W2 split) all failed to beat it. UNCHANGED.
// ---------------------------------------------------------------------------
__global__ __launch_bounds__(256, 2) void k_gemm7(const _Float16* __restrict__ Ap,
                                                  const _Float16* __restrict__ Bph,
                                                  const _Float16* __restrict__ Bpl,
                                                  const float* __restrict__ bias,
                                                  float* __restrict__ C) {
    __shared__ _Float16 AF[2][2][4][512];   // [buf][subkt][mt][lane*8]: 16 KB

    int n0 = blockIdx.x * 128;
    int m0 = blockIdx.y * 64;
    int t = threadIdx.x;
    int w = t >> 6, lane = t & 63;
    int lm = lane & 15, kq = lane >> 4;
    int wn = w * 32;

    int mt0 = m0 >> 4;
    int nt0 = (n0 + wn) >> 4;

    const _Float16* ag  = Ap  + (size_t)(mt0 + w) * 65536 + (size_t)lane * 8;
    const _Float16* bh0 = Bph + (size_t)nt0 * 65536 + (size_t)lane * 8;
    const _Float16* bh1 = Bph + (size_t)(nt0 + 1) * 65536 + (size_t)lane * 8;
    const _Float16* bl0 = Bpl + (size_t)nt0 * 65536 + (size_t)lane * 8;
    const _Float16* bl1 = Bpl + (size_t)(nt0 + 1) * 65536 + (size_t)lane * 8;

    f32x4 accH[4][2] = {}, accL[4][2] = {};

    // prologue: A + B regs for ktp = 0
    f16x8 r0 = *(const f16x8*)(ag);
    f16x8 r1 = *(const f16x8*)(ag + 512);
    f16x8 B0h0 = *(const f16x8*)(bh0);
    f16x8 B0h1 = *(const f16x8*)(bh1);
    f16x8 B0l0 = *(const f16x8*)(bl0);
    f16x8 B0l1 = *(const f16x8*)(bl1);
    f16x8 B1h0 = *(const f16x8*)(bh0 + 512);
    f16x8 B1h1 = *(const f16x8*)(bh1 + 512);
    f16x8 B1l0 = *(const f16x8*)(bl0 + 512);
    f16x8 B1l1 = *(const f16x8*)(bl1 + 512);

    for (int ktp = 0; ktp < 64; ++ktp) {
        int buf = ktp & 1;
        *(f16x8*)&AF[buf][0][w][lane * 8] = r0;
        *(f16x8*)&AF[buf][1][w][lane * 8] = r1;
        __syncthreads();

        // prefetch iter ktp+1 -- issued right after the barrier so the
        // vmcnt(0) drain at the NEXT barrier only sees full-phase-old loads.
        int kn = (ktp + 1 < 64) ? ktp + 1 : 63;
        size_t o0 = (size_t)(2 * kn) * 512, o1 = o0 + 512;
        f16x8 nr0 = *(const f16x8*)(ag + o0);
        f16x8 nr1 = *(const f16x8*)(ag + o1);
        f16x8 nB0h0 = *(const f16x8*)(bh0 + o0);
        f16x8 nB0h1 = *(const f16x8*)(bh1 + o0);
        f16x8 nB0l0 = *(const f16x8*)(bl0 + o0);
        f16x8 nB0l1 = *(const f16x8*)(bl1 + o0);
        f16x8 nB1h0 = *(const f16x8*)(bh0 + o1);
        f16x8 nB1h1 = *(const f16x8*)(bh1 + o1);
        f16x8 nB1l0 = *(const f16x8*)(bl0 + o1);
        f16x8 nB1l1 = *(const f16x8*)(bl1 + o1);
        // Pin: scheduler may not sink the 10 loads below this point.
        __builtin_amdgcn_sched_barrier(0);

        f16x8 a0[4], a1[4];
#pragma unroll
        for (int fm = 0; fm < 4; ++fm) {
            a0[fm] = *(const f16x8*)&AF[buf][0][fm][lane * 8];
            a1[fm] = *(const f16x8*)&AF[buf][1][fm][lane * 8];
        }

#pragma unroll
        for (int fm = 0; fm < 4; ++fm) {
            accH[fm][0] = __builtin_amdgcn_mfma_f32_16x16x32_f16(a0[fm], B0h0, accH[fm][0], 0, 0, 0);
            accL[fm][0] = __builtin_amdgcn_mfma_f32_16x16x32_f16(a0[fm], B0l0, accL[fm][0], 0, 0, 0);
            accH[fm][1] = __builtin_amdgcn_mfma_f32_16x16x32_f16(a0[fm], B0h1, accH[fm][1], 0, 0, 0);
            accL[fm][1] = __builtin_amdgcn_mfma_f32_16x16x32_f16(a0[fm], B0l1, accL[fm][1], 0, 0, 0);
        }
#pragma unroll
        for (int fm = 0; fm < 4; ++fm) {
            accH[fm][0] = __builtin_amdgcn_mfma_f32_16x16x32_f16(a1[fm], B1h0, accH[fm][0], 0, 0, 0);
            accL[fm][0] = __builtin_amdgcn_mfma_f32_16x16x32_f16(a1[fm], B1l0, accL[fm][0], 0, 0, 0);
            accH[fm][1] = __builtin_amdgcn_mfma_f32_16x16x32_f16(a1[fm], B1h1, accH[fm][1], 0, 0, 0);
            accL[fm][1] = __builtin_amdgcn_mfma_f32_16x16x32_f16(a1[fm], B1l1, accL[fm][1], 0, 0, 0);
        }

        r0 = nr0; r1 = nr1;
        B0h0 = nB0h0; B0h1 = nB0h1; B0l0 = nB0l0; B0l1 = nB0l1;
        B1h0 = nB1h0; B1h1 = nB1h1; B1l0 = nB1l0; B1l1 = nB1l1;
    }

    const float ls = 1.0f / 2048.0f;
#pragma unroll
    for (int fm = 0; fm < 4; ++fm)
#pragma unroll
        for (int fn = 0; fn < 2; ++fn) {
            int n = n0 + wn + fn * 16 + lm;
            float bv = bias[n];
#pragma unroll
            for (int r = 0; r < 4; ++r) {
                int m = m0 + fm * 16 + kq * 4 + r;
                C[(size_t)m * NCORR + n] = accH[fm][fn][r] + ls * accL[fm][fn][r] + bv;
            }
        }
}

// ---------------------------------------------------------------------------
// f32 fallback GEMM (round-2 kernel, unchanged)
// ---------------------------------------------------------------------------
#define BM 64
#define BN 64
#define BK 32
__global__ __launch_bounds__(256) void k_gemm(const float* __restrict__ A,
                                              const float* __restrict__ Bm,
                                              const float* __restrict__ bias,
                                              float* __restrict__ C) {
    __shared__ float As[BK][68];
    __shared__ float Bs[BK][BN];
    int n0 = blockIdx.x * BN, m0 = blockIdx.y * BM;
    int tid = threadIdx.x;
    int tm = tid >> 4, tn = tid & 15;
    int am = tid >> 3, ak = (tid & 7) * 4;
    int bk = tid >> 4, bn = (tid & 15) * 4;
    float acc[4][4] = {};
    for (int k0 = 0; k0 < HID; k0 += BK) {
#pragma unroll
        for (int s = 0; s < 2; ++s) {
            int m = am + 32 * s;
            float4 v = *(const float4*)(A + (size_t)(m0 + m) * HID + k0 + ak);
            As[ak + 0][m] = v.x; As[ak + 1][m] = v.y;
            As[ak + 2][m] = v.z; As[ak + 3][m] = v.w;
        }
#pragma unroll
        for (int s = 0; s < 2; ++s) {
            int k = bk + 16 * s;
            float4 v = *(const float4*)(Bm + (size_t)(k0 + k) * NCORR + n0 + bn);
            *(float4*)&Bs[k][bn] = v;
        }
        __syncthreads();
#pragma unroll
        for (int kk = 0; kk < BK; ++kk) {
            float4 a = *(const float4*)&As[kk][tm * 4];
            float4 bv = *(const float4*)&Bs[kk][tn * 4];
            float av[4] = {a.x, a.y, a.z, a.w};
            float bb[4] = {bv.x, bv.y, bv.z, bv.w};
#pragma unroll
            for (int i = 0; i < 4; ++i)
#pragma unroll
                for (int j = 0; j < 4; ++j) acc[i][j] += av[i] * bb[j];
        }
        __syncthreads();
    }
#pragma unroll
    for (int i = 0; i < 4; ++i) {
        int m = m0 + tm * 4 + i;
        float4 o;
        o.x = acc[i][0] + bias[n0 + tn * 4 + 0];
        o.y = acc[i][1] + bias[n0 + tn * 4 + 1];
        o.z = acc[i][2] + bias[n0 + tn * 4 + 2];
        o.w = acc[i][3] + bias[n0 + tn * 4 + 3];
        *(float4*)(C + (size_t)m * NCORR + n0 + tn * 4) = o;
    }
}

// ---------------------------------------------------------------------------
// Kernel C: gather + 32x32 LU (partial pivoting) per spin, planar complex out.
// ---------------------------------------------------------------------------
__global__ __launch_bounds__(128) void k_det(const int* __restrict__ x,
                                             const float* __restrict__ orbitals,
                                             const float* __restrict__ corr,
                                             float* __restrict__ out,
                                             int imag_off) {
    int b = blockIdx.x, tid = threadIdx.x;
    __shared__ int sx[NORB];
    __shared__ int yup[NUP], ydn[NUP];
    __shared__ float M[2][NUP][NUP + 1];
    __shared__ float rlog[2];
    __shared__ int rneg[2];

    sx[tid] = x[b * NORB + tid];
    __syncthreads();

    int occ = sx[tid];
    if (occ & 1) {
        int r = 0;
        for (int i = 0; i < tid; ++i) r += sx[i] & 1;
        yup[r] = tid;
    }
    if (occ & 2) {
        int r = 0;
        for (int i = 0; i < tid; ++i) r += (sx[i] >> 1) & 1;
        ydn[r] = tid;
    }
    __syncthreads();

    const float* cb = corr + (size_t)b * NCORR;
    for (int idx = tid; idx < 2 * NUP * NUP; idx += 128) {
        int s = idx >> 10;
        int i = (idx >> 5) & 31;
        int j = idx & 31;
        int r = s ? ydn[i] : yup[i];
        M[s][i][j] = orbitals[r * NUP + j] + cb[r * NUP + j];
    }
    __syncthreads();

    int wv = tid >> 6, lane = tid & 63;
    float (*Mm)[NUP + 1] = M[wv];
    float logdet = 0.f;
    int neg = 0;

    for (int k = 0; k < NUP; ++k) {
        float v = (lane >= k && lane < NUP) ? fabsf(Mm[lane][k]) : -1.f;
        int pi = lane;
#pragma unroll
        for (int off = 32; off > 0; off >>= 1) {
            float v2 = __shfl_down(v, off);
            int p2 = __shfl_down(pi, off);
            if (v2 > v) { v = v2; pi = p2; }
        }
        int p = __shfl(pi, 0);

        if (p != k) {
            if (lane < NUP) {
                float t1 = Mm[k][lane];
                Mm[k][lane] = Mm[p][lane];
                Mm[p][lane] = t1;
            }
            neg ^= 1;
        }
        __syncthreads();

        float pv = Mm[k][k];
        logdet += logf(fabsf(pv));
        if (pv < 0.f) neg ^= 1;

        int row = k + 1 + (lane & 31);
        int half = lane >> 5;
        if (row < NUP) {
            float f = Mm[row][k] / pv;
            for (int j = k + 1 + half; j < NUP; j += 2)
                Mm[row][j] -= f * Mm[k][j];
        }
        __syncthreads();
    }

    if (lane == 0) { rlog[wv] = logdet; rneg[wv] = neg; }
    __syncthreads();
    if (tid == 0) {
        out[b] = rlog[0] + rlog[1];
        if (imag_off > 0)
            out[imag_off + b] =
                (rneg[0] ^ rneg[1]) ? 3.14159265358979323846f : 0.f;
    }
}

// ---------------------------------------------------------------------------
extern "C" void kernel_launch(void* const* d_in, const int* in_sizes, int n_in,
                              void* d_out, int out_size, void* d_ws, size_t ws_size,
                              hipStream_t stream) {
    const int*   x        = (const int*)d_in[0];
    const float* orbitals = (const float*)d_in[1];
    const float* W1       = (const float*)d_in[2];
    const float* b1       = (const float*)d_in[3];
    const float* W2       = (const float*)d_in[4];
    const float* b2       = (const float*)d_in[5];
    float* out = (float*)d_out;
    int imag_off = (out_size == 2 * B_SZ) ? B_SZ : 0;

    const size_t need = (size_t)96 * 1024 * 1024;
    if (ws_size >= need) {
        _Float16* h16  = (_Float16*)d_ws;                                //  8 MB (A-frag packed f16)
        _Float16* Bh16 = h16 + (size_t)B_SZ * HID;                       // 32 MB (W2 hi f16, B-frag)
        _Float16* Bl16 = Bh16 + (size_t)HID * NCORR;                     // 32 MB (W2 lo*2048 f16)
        float*    corr = (float*)(Bl16 + (size_t)HID * NCORR);           // 16 MB

        // W1-pack (bf16) lives INSIDE corr — written by k_pack, read by
        // k_hidden3, overwritten later by k_gemm7's corr output.
        unsigned short* W1ph = (unsigned short*)corr;                    // 4 MB
        unsigned short* W1pl = W1ph + (size_t)K1 * HID;                  // 4 MB

        // 1) MERGED pack: W1 (blocks 0..1023) + W2 (blocks 1024..9215)
        k_pack<<<1024 + 8192, 256, 0, stream>>>(W1, W1ph, W1pl,
                                                W2, Bh16, Bl16);

        // 2) hidden layer
        k_hidden3<<<dim3(HID / 128, B_SZ / 64), 256, 0, stream>>>(x, W1ph, W1pl, b1, h16);

        // 3) main GEMM
        dim3 g2(NCORR / 128, B_SZ / 64);    // 32 x 16 = 512 blocks
        k_gemm7<<<g2, 256, 0, stream>>>(h16, Bh16, Bl16, b2, corr);

        // 4) determinants
        k_det<<<B_SZ, 128, 0, stream>>>(x, orbitals, corr, out, imag_off);
    } else {
        float* h    = (float*)d_ws;
        float* corr = h + (size_t)B_SZ * HID;
        k_hidden_f32<<<B_SZ, 256, 0, stream>>>(x, W1, b1, h);
        dim3 g2(NCORR / BN, B_SZ / BM);
        k_gemm<<<g2, 256, 0, stream>>>(h, W2, b2, corr);
        k_det<<<B_SZ, 128, 0, stream>>>(x, orbitals, corr, out, imag_off);
    }
}

// Round 10
// 235.871 us; speedup vs baseline: 2.0521x; 1.0148x over previous
//
#include <hip/hip_runtime.h>
#include <cmath>

#define B_SZ  1024
#define NORB  128
#define NUP   32
#define HID   4096
#define NCORR (NORB * NUP)   // 4096
#define K1    (4 * NORB)     // 512, one-hot GEMM K-dim

typedef short    bf16x8 __attribute__((ext_vector_type(8)));
typedef _Float16 f16x8  __attribute__((ext_vector_type(8)));
typedef float    f32x4  __attribute__((ext_vector_type(4)));

__device__ __forceinline__ unsigned short f2bf_rne(float f) {
    unsigned int u = __float_as_uint(f);
    u += 0x7FFFu + ((u >> 16) & 1u);
    return (unsigned short)(u >> 16);
}

// ---------------------------------------------------------------------------
// k_pack: MERGED W1-pack + W2-pack (r8/r9 verified).
//   blocks [0,1024):    W1 [512][4096] -> bf16 hi/lo, B-frag order, ktTot=16
//   blocks [1024,9216): W2 [4096][4096] -> f16 hi + f16 lo*2048, ktTot=128
// lo*2048 keeps W2_lo in f16 normal range; gemm7 epilogue applies 1/2048.
// ---------------------------------------------------------------------------
__global__ __launch_bounds__(256) void k_pack(const float* __restrict__ W1,
                                              unsigned short* __restrict__ W1ph,
                                              unsigned short* __restrict__ W1pl,
                                              const float* __restrict__ W2,
                                              _Float16* __restrict__ Bh16,
                                              _Float16* __restrict__ Bl16) {
    __shared__ float tile[64][33];
    int bid = blockIdx.x;
    int t = threadIdx.x;

    int isW2 = (bid >= 1024);
    int i = isW2 ? bid - 1024 : bid;
    int n0 = (i & 127) * 32;
    int k0 = (i >> 7) * 64;
    const float* W = isW2 ? W2 : W1;

    int rl = t >> 3, c4 = (t & 7) * 4;
#pragma unroll
    for (int q = 0; q < 2; ++q) {
        int kl = rl + 32 * q;
        float4 v = *(const float4*)(W + (size_t)(k0 + kl) * 4096 + n0 + c4);
        tile[kl][c4 + 0] = v.x; tile[kl][c4 + 1] = v.y;
        tile[kl][c4 + 2] = v.z; tile[kl][c4 + 3] = v.w;
    }
    __syncthreads();

    int nl = t & 31, kg = t >> 5;
    int nt = (n0 + nl) >> 4;
    int kt = (k0 >> 5) + (kg >> 2);
    int lane_o = (kg & 3) * 16 + (nl & 15);

    if (isW2) {
        size_t o = (((size_t)nt * 128 + kt) * 64 + lane_o) * 8;
        f16x8 hi8, lo8;
#pragma unroll
        for (int j = 0; j < 8; ++j) {
            float v = tile[kg * 8 + j][nl];
            _Float16 hi = (_Float16)v;
            hi8[j] = hi;
            lo8[j] = (_Float16)((v - (float)hi) * 2048.0f);
        }
        *(f16x8*)(Bh16 + o) = hi8;
        *(f16x8*)(Bl16 + o) = lo8;
    } else {
        size_t o = (((size_t)nt * 16 + kt) * 64 + lane_o) * 8;
        unsigned short hi8[8], lo8[8];
#pragma unroll
        for (int j = 0; j < 8; ++j) {
            float v = tile[kg * 8 + j][nl];
            unsigned short hi = f2bf_rne(v);
            float fhi = __uint_as_float((unsigned int)hi << 16);
            hi8[j] = hi;
            lo8[j] = f2bf_rne(v - fhi);
        }
        *(bf16x8*)(W1ph + o) = *(bf16x8*)hi8;
        *(bf16x8*)(W1pl + o) = *(bf16x8*)lo8;
    }
}

// ---------------------------------------------------------------------------
// k_hidden3: h = relu(one_hot(x) @ (W1hi + W1lo) + b1), f32 acc via bf16 MFMA.
// sched_barrier(0) pins the r0-r7 prefetch above the MFMA phase.
// (r3-verified version, unchanged.)
// ---------------------------------------------------------------------------
__global__ __launch_bounds__(256, 2) void k_hidden3(const int* __restrict__ x,
                                                    const unsigned short* __restrict__ Bph,
                                                    const unsigned short* __restrict__ Bpl,
                                                    const float* __restrict__ b1,
                                                    _Float16* __restrict__ h16) {
    __shared__ unsigned int sxp[64][8];                 //  2 KB
    __shared__ unsigned short BF[2][4][4][512];         // 32 KB
    __shared__ float Ht[64][132];                       // 33.8 KB

    int n0 = blockIdx.x * 128;
    int m0 = blockIdx.y * 64;
    int t = threadIdx.x;
    int w = t >> 6, lane = t & 63;
    int lm = lane & 15, kq = lane >> 4;
    int wn = w * 32;

    // pack x for this m-tile: 64 rows x 8 dwords (2 bits/orbital)
#pragma unroll
    for (int i = 0; i < 2; ++i) {
        int id = t + 256 * i;
        int row = id >> 3, d = id & 7;
        const int* src = x + (size_t)(m0 + row) * NORB + d * 16;
        unsigned int dw = 0;
#pragma unroll
        for (int b = 0; b < 16; ++b) dw |= ((unsigned int)(src[b] & 3)) << (2 * b);
        sxp[row][d] = dw;
    }

    int nt0 = (n0 + wn) >> 4;
    const unsigned short* bh0 = Bph + (size_t)nt0 * (16 * 512) + (size_t)lane * 8;
    const unsigned short* bh1 = Bph + (size_t)(nt0 + 1) * (16 * 512) + (size_t)lane * 8;
    const unsigned short* bl0 = Bpl + (size_t)nt0 * (16 * 512) + (size_t)lane * 8;
    const unsigned short* bl1 = Bpl + (size_t)(nt0 + 1) * (16 * 512) + (size_t)lane * 8;

    f32x4 acc[4][2] = {};

    bf16x8 r0 = *(const bf16x8*)(bh0);
    bf16x8 r1 = *(const bf16x8*)(bh1);
    bf16x8 r2 = *(const bf16x8*)(bl0);
    bf16x8 r3 = *(const bf16x8*)(bl1);
    bf16x8 r4 = *(const bf16x8*)(bh0 + 512);
    bf16x8 r5 = *(const bf16x8*)(bh1 + 512);
    bf16x8 r6 = *(const bf16x8*)(bl0 + 512);
    bf16x8 r7 = *(const bf16x8*)(bl1 + 512);

    __syncthreads();   // sxp ready

    for (int p = 0; p < 8; ++p) {
        if (p) __syncthreads();

        *(bf16x8*)&BF[0][w][0][lane * 8] = r0;
        *(bf16x8*)&BF[0][w][1][lane * 8] = r1;
        *(bf16x8*)&BF[0][w][2][lane * 8] = r2;
        *(bf16x8*)&BF[0][w][3][lane * 8] = r3;
        *(bf16x8*)&BF[1][w][0][lane * 8] = r4;
        *(bf16x8*)&BF[1][w][1][lane * 8] = r5;
        *(bf16x8*)&BF[1][w][2][lane * 8] = r6;
        *(bf16x8*)&BF[1][w][3][lane * 8] = r7;
        __syncthreads();

        int kn = (p + 1 < 8) ? p + 1 : 7;
        r0 = *(const bf16x8*)(bh0 + (2 * kn) * 512);
        r1 = *(const bf16x8*)(bh1 + (2 * kn) * 512);
        r2 = *(const bf16x8*)(bl0 + (2 * kn) * 512);
        r3 = *(const bf16x8*)(bl1 + (2 * kn) * 512);
        r4 = *(const bf16x8*)(bh0 + (2 * kn + 1) * 512);
        r5 = *(const bf16x8*)(bh1 + (2 * kn + 1) * 512);
        r6 = *(const bf16x8*)(bl0 + (2 * kn + 1) * 512);
        r7 = *(const bf16x8*)(bl1 + (2 * kn + 1) * 512);
        // Pin the prefetch ABOVE the MFMA phase.
        __builtin_amdgcn_sched_barrier(0);

#pragma unroll
        for (int s = 0; s < 2; ++s) {
            int kt = 2 * p + s;
            int i0 = kt * 8 + kq * 2;
            int dwIdx = i0 >> 4;
            int sh = (i0 & 15) * 2;
            bf16x8 af[4];
#pragma unroll
            for (int fm = 0; fm < 4; ++fm) {
                unsigned int dw = sxp[fm * 16 + lm][dwIdx];
                unsigned int c01 = (dw >> sh) & 0xFu;
                union { bf16x8 v; unsigned long long u[2]; } a;
                a.u[0] = 0x3F80ULL << ((c01 & 3u) * 16);
                a.u[1] = 0x3F80ULL << ((c01 >> 2) * 16);
                af[fm] = a.v;
            }

            bf16x8 b0h = *(const bf16x8*)&BF[s][w][0][lane * 8];
            bf16x8 b1h = *(const bf16x8*)&BF[s][w][1][lane * 8];
            bf16x8 b0l = *(const bf16x8*)&BF[s][w][2][lane * 8];
            bf16x8 b1l = *(const bf16x8*)&BF[s][w][3][lane * 8];

#pragma unroll
            for (int fm = 0; fm < 4; ++fm) {
                acc[fm][0] = __builtin_amdgcn_mfma_f32_16x16x32_bf16(af[fm], b0h, acc[fm][0], 0, 0, 0);
                acc[fm][0] = __builtin_amdgcn_mfma_f32_16x16x32_bf16(af[fm], b0l, acc[fm][0], 0, 0, 0);
                acc[fm][1] = __builtin_amdgcn_mfma_f32_16x16x32_bf16(af[fm], b1h, acc[fm][1], 0, 0, 0);
                acc[fm][1] = __builtin_amdgcn_mfma_f32_16x16x32_bf16(af[fm], b1l, acc[fm][1], 0, 0, 0);
            }
        }
    }

    // epilogue: bias+relu into LDS (D-layout), read back in A-frag order, f16
    __syncthreads();
#pragma unroll
    for (int fm = 0; fm < 4; ++fm)
#pragma unroll
        for (int fn = 0; fn < 2; ++fn) {
            int n = wn + fn * 16 + lm;
            float bv = b1[n0 + n];
#pragma unroll
            for (int r = 0; r < 4; ++r)
                Ht[fm * 16 + kq * 4 + r][n] = fmaxf(acc[fm][fn][r] + bv, 0.f);
        }
    __syncthreads();

    size_t mt0 = (size_t)(m0 >> 4), kt0 = (size_t)(n0 >> 5);
#pragma unroll
    for (int fi = 0; fi < 4; ++fi) {
        int f = w * 4 + fi;
        int mt = f >> 2, ktn = f & 3;
        int m = mt * 16 + lm;
        int kn = ktn * 32 + kq * 8;
        float4 v0 = *(const float4*)&Ht[m][kn];
        float4 v1 = *(const float4*)&Ht[m][kn + 4];
        float vv[8] = {v0.x, v0.y, v0.z, v0.w, v1.x, v1.y, v1.z, v1.w};
        f16x8 o16;
#pragma unroll
        for (int j = 0; j < 8; ++j) o16[j] = (_Float16)vv[j];
        size_t o = (((mt0 + mt) * 128 + (kt0 + ktn)) * 64 + lane) * 8;
        *(f16x8*)(h16 + o) = o16;
    }
}

// ---------------------------------------------------------------------------
// f32 fallback hidden
// ---------------------------------------------------------------------------
__global__ __launch_bounds__(256) void k_hidden_f32(const int* __restrict__ x,
                                                    const float* __restrict__ W1,
                                                    const float* __restrict__ b1,
                                                    float* __restrict__ h) {
    int b = blockIdx.x, tid = threadIdx.x;
    __shared__ int sx[NORB];
    if (tid < NORB) sx[tid] = x[b * NORB + tid];
    __syncthreads();
    float acc[16];
#pragma unroll
    for (int u = 0; u < 16; ++u) acc[u] = b1[tid + 256 * u];
    for (int i = 0; i < NORB; ++i) {
        const float* row = W1 + (size_t)(4 * i + sx[i]) * HID;
#pragma unroll
        for (int u = 0; u < 16; ++u) acc[u] += row[tid + 256 * u];
    }
    float* hb = h + (size_t)b * HID;
#pragma unroll
    for (int u = 0; u < 16; ++u) hb[tid + 256 * u] = fmaxf(acc[u], 0.f);
}

// ---------------------------------------------------------------------------
// k_gemm7: corr = h16 @ W2hi16 + (h16 @ W2lo16')/2048 + b2, f16 MFMA, f32 acc.
// r3-verified core (unchanged). ROUND-POLISH r9: XCD-LOCALITY SWIZZLE.
// Probe: the invariant ~32B/cyc/CU delivery cap (r1-r5) is either a per-CU
// return-path cap or L3/fabric contention. Current order round-robins n-tiles
// over XCDs -> every B-read misses the 4MB per-XCD L2 and hits L3 (aggregate
// 19.7 TB/s ~ plausible L3 ceiling). Remap: hardware wg h runs on XCD h%8
// (m09/m157); lb=(h&7)*64+(h>>3) gives XCD x the 64 co-resident blocks
// covering n-tiles 4x..4x+3 x all 16 m. The 16 same-n blocks march through
// B in near-lockstep -> each 32KB K-window fetched to L2 once, hit 16x.
// Bijective (512%8==0). If L3-bound: dur 68->~55. If CU-cap: null (closes
// the hypothesis).
// ---------------------------------------------------------------------------
__global__ __launch_bounds__(256, 2) void k_gemm7(const _Float16* __restrict__ Ap,
                                                  const _Float16* __restrict__ Bph,
                                                  const _Float16* __restrict__ Bpl,
                                                  const float* __restrict__ bias,
                                                  float* __restrict__ C) {
    __shared__ _Float16 AF[2][2][4][512];   // [buf][subkt][mt][lane*8]: 16 KB

    // XCD-locality swizzle: hw bid -> logical (nIdx, mIdx)
    int bid = blockIdx.x;                 // 0..511
    int lb = (bid & 7) * 64 + (bid >> 3); // XCD (bid&7) gets lb in [x*64,x*64+64)
    int local = lb & 63;
    int n0 = ((lb >> 6) * 4 + (local >> 4)) * 128;
    int m0 = (local & 15) * 64;

    int t = threadIdx.x;
    int w = t >> 6, lane = t & 63;
    int lm = lane & 15, kq = lane >> 4;
    int wn = w * 32;

    int mt0 = m0 >> 4;
    int nt0 = (n0 + wn) >> 4;

    const _Float16* ag  = Ap  + (size_t)(mt0 + w) * 65536 + (size_t)lane * 8;
    const _Float16* bh0 = Bph + (size_t)nt0 * 65536 + (size_t)lane * 8;
    const _Float16* bh1 = Bph + (size_t)(nt0 + 1) * 65536 + (size_t)lane * 8;
    const _Float16* bl0 = Bpl + (size_t)nt0 * 65536 + (size_t)lane * 8;
    const _Float16* bl1 = Bpl + (size_t)(nt0 + 1) * 65536 + (size_t)lane * 8;

    f32x4 accH[4][2] = {}, accL[4][2] = {};

    // prologue: A + B regs for ktp = 0
    f16x8 r0 = *(const f16x8*)(ag);
    f16x8 r1 = *(const f16x8*)(ag + 512);
    f16x8 B0h0 = *(const f16x8*)(bh0);
    f16x8 B0h1 = *(const f16x8*)(bh1);
    f16x8 B0l0 = *(const f16x8*)(bl0);
    f16x8 B0l1 = *(const f16x8*)(bl1);
    f16x8 B1h0 = *(const f16x8*)(bh0 + 512);
    f16x8 B1h1 = *(const f16x8*)(bh1 + 512);
    f16x8 B1l0 = *(const f16x8*)(bl0 + 512);
    f16x8 B1l1 = *(const f16x8*)(bl1 + 512);

    for (int ktp = 0; ktp < 64; ++ktp) {
        int buf = ktp & 1;
        *(f16x8*)&AF[buf][0][w][lane * 8] = r0;
        *(f16x8*)&AF[buf][1][w][lane * 8] = r1;
        __syncthreads();

        // prefetch iter ktp+1 -- issued right after the barrier so the
        // vmcnt(0) drain at the NEXT barrier only sees full-phase-old loads.
        int kn = (ktp + 1 < 64) ? ktp + 1 : 63;
        size_t o0 = (size_t)(2 * kn) * 512, o1 = o0 + 512;
        f16x8 nr0 = *(const f16x8*)(ag + o0);
        f16x8 nr1 = *(const f16x8*)(ag + o1);
        f16x8 nB0h0 = *(const f16x8*)(bh0 + o0);
        f16x8 nB0h1 = *(const f16x8*)(bh1 + o0);
        f16x8 nB0l0 = *(const f16x8*)(bl0 + o0);
        f16x8 nB0l1 = *(const f16x8*)(bl1 + o0);
        f16x8 nB1h0 = *(const f16x8*)(bh0 + o1);
        f16x8 nB1h1 = *(const f16x8*)(bh1 + o1);
        f16x8 nB1l0 = *(const f16x8*)(bl0 + o1);
        f16x8 nB1l1 = *(const f16x8*)(bl1 + o1);
        // Pin: scheduler may not sink the 10 loads below this point.
        __builtin_amdgcn_sched_barrier(0);

        f16x8 a0[4], a1[4];
#pragma unroll
        for (int fm = 0; fm < 4; ++fm) {
            a0[fm] = *(const f16x8*)&AF[buf][0][fm][lane * 8];
            a1[fm] = *(const f16x8*)&AF[buf][1][fm][lane * 8];
        }

#pragma unroll
        for (int fm = 0; fm < 4; ++fm) {
            accH[fm][0] = __builtin_amdgcn_mfma_f32_16x16x32_f16(a0[fm], B0h0, accH[fm][0], 0, 0, 0);
            accL[fm][0] = __builtin_amdgcn_mfma_f32_16x16x32_f16(a0[fm], B0l0, accL[fm][0], 0, 0, 0);
            accH[fm][1] = __builtin_amdgcn_mfma_f32_16x16x32_f16(a0[fm], B0h1, accH[fm][1], 0, 0, 0);
            accL[fm][1] = __builtin_amdgcn_mfma_f32_16x16x32_f16(a0[fm], B0l1, accL[fm][1], 0, 0, 0);
        }
#pragma unroll
        for (int fm = 0; fm < 4; ++fm) {
            accH[fm][0] = __builtin_amdgcn_mfma_f32_16x16x32_f16(a1[fm], B1h0, accH[fm][0], 0, 0, 0);
            accL[fm][0] = __builtin_amdgcn_mfma_f32_16x16x32_f16(a1[fm], B1l0, accL[fm][0], 0, 0, 0);
            accH[fm][1] = __builtin_amdgcn_mfma_f32_16x16x32_f16(a1[fm], B1h1, accH[fm][1], 0, 0, 0);
            accL[fm][1] = __builtin_amdgcn_mfma_f32_16x16x32_f16(a1[fm], B1l1, accL[fm][1], 0, 0, 0);
        }

        r0 = nr0; r1 = nr1;
        B0h0 = nB0h0; B0h1 = nB0h1; B0l0 = nB0l0; B0l1 = nB0l1;
        B1h0 = nB1h0; B1h1 = nB1h1; B1l0 = nB1l0; B1l1 = nB1l1;
    }

    const float ls = 1.0f / 2048.0f;
#pragma unroll
    for (int fm = 0; fm < 4; ++fm)
#pragma unroll
        for (int fn = 0; fn < 2; ++fn) {
            int n = n0 + wn + fn * 16 + lm;
            float bv = bias[n];
#pragma unroll
            for (int r = 0; r < 4; ++r) {
                int m = m0 + fm * 16 + kq * 4 + r;
                C[(size_t)m * NCORR + n] = accH[fm][fn][r] + ls * accL[fm][fn][r] + bv;
            }
        }
}

// ---------------------------------------------------------------------------
// f32 fallback GEMM (round-2 kernel, unchanged)
// ---------------------------------------------------------------------------
#define BM 64
#define BN 64
#define BK 32
__global__ __launch_bounds__(256) void k_gemm(const float* __restrict__ A,
                                              const float* __restrict__ Bm,
                                              const float* __restrict__ bias,
                                              float* __restrict__ C) {
    __shared__ float As[BK][68];
    __shared__ float Bs[BK][BN];
    int n0 = blockIdx.x * BN, m0 = blockIdx.y * BM;
    int tid = threadIdx.x;
    int tm = tid >> 4, tn = tid & 15;
    int am = tid >> 3, ak = (tid & 7) * 4;
    int bk = tid >> 4, bn = (tid & 15) * 4;
    float acc[4][4] = {};
    for (int k0 = 0; k0 < HID; k0 += BK) {
#pragma unroll
        for (int s = 0; s < 2; ++s) {
            int m = am + 32 * s;
            float4 v = *(const float4*)(A + (size_t)(m0 + m) * HID + k0 + ak);
            As[ak + 0][m] = v.x; As[ak + 1][m] = v.y;
            As[ak + 2][m] = v.z; As[ak + 3][m] = v.w;
        }
#pragma unroll
        for (int s = 0; s < 2; ++s) {
            int k = bk + 16 * s;
            float4 v = *(const float4*)(Bm + (size_t)(k0 + k) * NCORR + n0 + bn);
            *(float4*)&Bs[k][bn] = v;
        }
        __syncthreads();
#pragma unroll
        for (int kk = 0; kk < BK; ++kk) {
            float4 a = *(const float4*)&As[kk][tm * 4];
            float4 bv = *(const float4*)&Bs[kk][tn * 4];
            float av[4] = {a.x, a.y, a.z, a.w};
            float bb[4] = {bv.x, bv.y, bv.z, bv.w};
#pragma unroll
            for (int i = 0; i < 4; ++i)
#pragma unroll
                for (int j = 0; j < 4; ++j) acc[i][j] += av[i] * bb[j];
        }
        __syncthreads();
    }
#pragma unroll
    for (int i = 0; i < 4; ++i) {
        int m = m0 + tm * 4 + i;
        float4 o;
        o.x = acc[i][0] + bias[n0 + tn * 4 + 0];
        o.y = acc[i][1] + bias[n0 + tn * 4 + 1];
        o.z = acc[i][2] + bias[n0 + tn * 4 + 2];
        o.w = acc[i][3] + bias[n0 + tn * 4 + 3];
        *(float4*)(C + (size_t)m * NCORR + n0 + tn * 4) = o;
    }
}

// ---------------------------------------------------------------------------
// Kernel C: gather + 32x32 LU (partial pivoting) per spin, planar complex out.
// ROUND-POLISH r9: ballot-based electron ranking replaces the O(NORB) serial
// per-thread loops (exact same result; wave0's counts passed via LDS).
// ---------------------------------------------------------------------------
__global__ __launch_bounds__(128) void k_det(const int* __restrict__ x,
                                             const float* __restrict__ orbitals,
                                             const float* __restrict__ corr,
                                             float* __restrict__ out,
                                             int imag_off) {
    int b = blockIdx.x, tid = threadIdx.x;
    __shared__ int yup[NUP], ydn[NUP];
    __shared__ int cnt0[2];
    __shared__ float M[2][NUP][NUP + 1];
    __shared__ float rlog[2];
    __shared__ int rneg[2];

    int occ = x[b * NORB + tid];
    int lane0 = tid & 63;
    unsigned long long mup = __ballot(occ & 1);
    unsigned long long mdn = __ballot((occ >> 1) & 1);
    if (tid == 0) { cnt0[0] = __popcll(mup); cnt0[1] = __popcll(mdn); }
    __syncthreads();

    unsigned long long below = (1ull << lane0) - 1ull;
    int bu = (tid >= 64) ? cnt0[0] : 0;
    int bd = (tid >= 64) ? cnt0[1] : 0;
    if (occ & 1) yup[bu + __popcll(mup & below)] = tid;
    if (occ & 2) ydn[bd + __popcll(mdn & below)] = tid;
    __syncthreads();

    const float* cb = corr + (size_t)b * NCORR;
    for (int idx = tid; idx < 2 * NUP * NUP; idx += 128) {
        int s = idx >> 10;
        int i = (idx >> 5) & 31;
        int j = idx & 31;
        int r = s ? ydn[i] : yup[i];
        M[s][i][j] = orbitals[r * NUP + j] + cb[r * NUP + j];
    }
    __syncthreads();

    int wv = tid >> 6, lane = tid & 63;
    float (*Mm)[NUP + 1] = M[wv];
    float logdet = 0.f;
    int neg = 0;

    for (int k = 0; k < NUP; ++k) {
        float v = (lane >= k && lane < NUP) ? fabsf(Mm[lane][k]) : -1.f;
        int pi = lane;
#pragma unroll
        for (int off = 32; off > 0; off >>= 1) {
            float v2 = __shfl_down(v, off);
            int p2 = __shfl_down(pi, off);
            if (v2 > v) { v = v2; pi = p2; }
        }
        int p = __shfl(pi, 0);

        if (p != k) {
            if (lane < NUP) {
                float t1 = Mm[k][lane];
                Mm[k][lane] = Mm[p][lane];
                Mm[p][lane] = t1;
            }
            neg ^= 1;
        }
        __syncthreads();

        float pv = Mm[k][k];
        logdet += logf(fabsf(pv));
        if (pv < 0.f) neg ^= 1;

        int row = k + 1 + (lane & 31);
        int half = lane >> 5;
        if (row < NUP) {
            float f = Mm[row][k] / pv;
            for (int j = k + 1 + half; j < NUP; j += 2)
                Mm[row][j] -= f * Mm[k][j];
        }
        __syncthreads();
    }

    if (lane == 0) { rlog[wv] = logdet; rneg[wv] = neg; }
    __syncthreads();
    if (tid == 0) {
        out[b] = rlog[0] + rlog[1];
        if (imag_off > 0)
            out[imag_off + b] =
                (rneg[0] ^ rneg[1]) ? 3.14159265358979323846f : 0.f;
    }
}

// ---------------------------------------------------------------------------
extern "C" void kernel_launch(void* const* d_in, const int* in_sizes, int n_in,
                              void* d_out, int out_size, void* d_ws, size_t ws_size,
                              hipStream_t stream) {
    const int*   x        = (const int*)d_in[0];
    const float* orbitals = (const float*)d_in[1];
    const float* W1       = (const float*)d_in[2];
    const float* b1       = (const float*)d_in[3];
    const float* W2       = (const float*)d_in[4];
    const float* b2       = (const float*)d_in[5];
    float* out = (float*)d_out;
    int imag_off = (out_size == 2 * B_SZ) ? B_SZ : 0;

    const size_t need = (size_t)96 * 1024 * 1024;
    if (ws_size >= need) {
        _Float16* h16  = (_Float16*)d_ws;                                //  8 MB (A-frag packed f16)
        _Float16* Bh16 = h16 + (size_t)B_SZ * HID;                       // 32 MB (W2 hi f16, B-frag)
        _Float16* Bl16 = Bh16 + (size_t)HID * NCORR;                     // 32 MB (W2 lo*2048 f16)
        float*    corr = (float*)(Bl16 + (size_t)HID * NCORR);           // 16 MB

        // W1-pack (bf16) lives INSIDE corr — written by k_pack, read by
        // k_hidden3, overwritten later by k_gemm7's corr output.
        unsigned short* W1ph = (unsigned short*)corr;                    // 4 MB
        unsigned short* W1pl = W1ph + (size_t)K1 * HID;                  // 4 MB

        // 1) MERGED pack: W1 (blocks 0..1023) + W2 (blocks 1024..9215)
        k_pack<<<1024 + 8192, 256, 0, stream>>>(W1, W1ph, W1pl,
                                                W2, Bh16, Bl16);

        // 2) hidden layer
        k_hidden3<<<dim3(HID / 128, B_SZ / 64), 256, 0, stream>>>(x, W1ph, W1pl, b1, h16);

        // 3) main GEMM (1-D grid, XCD-locality swizzle inside kernel)
        k_gemm7<<<512, 256, 0, stream>>>(h16, Bh16, Bl16, b2, corr);

        // 4) determinants
        k_det<<<B_SZ, 128, 0, stream>>>(x, orbitals, corr, out, imag_off);
    } else {
        float* h    = (float*)d_ws;
        float* corr = h + (size_t)B_SZ * HID;
        k_hidden_f32<<<B_SZ, 256, 0, stream>>>(x, W1, b1, h);
        dim3 g2(NCORR / BN, B_SZ / BM);
        k_gemm<<<g2, 256, 0, stream>>>(h, W2, b2, corr);
        k_det<<<B_SZ, 128, 0, stream>>>(x, orbitals, corr, out, imag_off);
    }
}